// Round 1
// 689.591 us; speedup vs baseline: 1.2376x; 1.2376x over previous
//
#include <hip/hip_runtime.h>
#include <hip/hip_bf16.h>

namespace {

constexpr int Bc = 2, Hc = 16, Sc = 2048, Dc = 64;
constexpr float kScale = 0.125f;   // 1/sqrt(64)
constexpr int KC = 64;             // keys per chunk
constexpr int NT = Sc / KC;        // 32 chunks

typedef __attribute__((ext_vector_type(8))) short bf16x8;
typedef __attribute__((ext_vector_type(4))) short s16x4;
typedef __attribute__((ext_vector_type(4))) float f32x4;

__device__ inline short f2bf(float x) {
    union { float f; unsigned int u; } v;
    v.f = x;
    unsigned int r = v.u + 0x7fffu + ((v.u >> 16) & 1u);
    return (short)(r >> 16);
}

// async global->LDS, 16B per lane; LDS dest must be wave-uniform base + lane*16
__device__ inline void gload16(const void* g, void* l) {
    typedef __attribute__((address_space(1))) const unsigned int GU;
    typedef __attribute__((address_space(3))) unsigned int LU;
    __builtin_amdgcn_global_load_lds((GU*)g, (LU*)l, 16, 0, 0);
}

// -------- prep: K -> bf16 (row-major, swizzled), V -> bf16 transposed [D][S] (swizzled)
// swizzle: element (row, col-within-64) stored at slot col ^ ((row&7)<<3)  [shorts]
__global__ __launch_bounds__(256)
void prep(const float* __restrict__ kg, const float* __restrict__ vg,
          unsigned short* __restrict__ kb, unsigned short* __restrict__ vtb) {
    const int tid = (int)threadIdx.x;
    const int bh = (int)blockIdx.y;
    const int k0 = (int)blockIdx.x * KC;
    const float* kh = kg + (size_t)bh * Sc * Dc;
    const float* vh = vg + (size_t)bh * Sc * Dc;
    unsigned short* kbh = kb + (size_t)bh * Sc * Dc;           // [S][D] swizzled in D
    unsigned short* vth = vtb + (size_t)bh * Sc * Dc;          // [D][S] swizzled in key%64

    __shared__ float sv[64][65];

    #pragma unroll
    for (int it = 0; it < 4; ++it) {
        int fid = tid + it * 256;
        int row = fid >> 4;          // key within tile
        int c4  = (fid & 15) * 4;    // d
        int key = k0 + row;
        float4 tk = *(const float4*)(kh + (size_t)key * Dc + c4);
        int dsw = c4 ^ ((key & 7) << 3);     // (c4+i)^s stays a contiguous run of 4
        s16x4 kv;
        kv[0] = f2bf(tk.x); kv[1] = f2bf(tk.y); kv[2] = f2bf(tk.z); kv[3] = f2bf(tk.w);
        *(s16x4*)(kbh + (size_t)key * Dc + dsw) = kv;
        float4 tv = *(const float4*)(vh + (size_t)key * Dc + c4);
        sv[row][c4 + 0] = tv.x; sv[row][c4 + 1] = tv.y;
        sv[row][c4 + 2] = tv.z; sv[row][c4 + 3] = tv.w;
    }
    __syncthreads();

    // transpose V tile: thread owns one d-row, 16 keys; swizzled slots split into two 8-runs
    const int d = tid >> 2;
    const int key16 = (tid & 3) * 16;
    const int s = (d & 7) << 3;
    const int base = key16 ^ (s & 48);
    const int b0 = base + (s & 8);          // keys key16+0..7  -> slots b0..b0+7
    const int b1 = base + ((s & 8) ^ 8);    // keys key16+8..15 -> slots b1..b1+7
    bf16x8 r0, r1;
    #pragma unroll
    for (int i = 0; i < 8; ++i) {
        r0[i] = f2bf(sv[key16 + i][d]);
        r1[i] = f2bf(sv[key16 + 8 + i][d]);
    }
    *(bf16x8*)(vth + (size_t)d * Sc + k0 + b0) = r0;
    *(bf16x8*)(vth + (size_t)d * Sc + k0 + b1) = r1;
}

// -------- staging helpers (linear LDS, pre-swizzled global source)
__device__ inline void stage_k_tile(const unsigned short* kbh, int k0,
                                    unsigned short* dst, int tid) {
    const unsigned short* src = kbh + (size_t)k0 * Dc;   // 8KB contiguous tile
    gload16(src + tid * 8, dst + tid * 8);
    gload16(src + 2048 + tid * 8, dst + 2048 + tid * 8);
}
__device__ inline void stage_vt_tile(const unsigned short* vth, int k0,
                                     unsigned short* dst, int tid) {
    int r = tid >> 3, c8 = (tid & 7) * 8;
    gload16(vth + (size_t)r * Sc + k0 + c8, dst + r * 64 + c8);
    gload16(vth + (size_t)(r + 32) * Sc + k0 + c8, dst + (r + 32) * 64 + c8);
}

__global__ __launch_bounds__(256, 4)
void fa_fwd(const float* __restrict__ qg, const unsigned short* __restrict__ kb,
            const unsigned short* __restrict__ vtb, float* __restrict__ outg,
            float* __restrict__ attng) {
    const int tid  = (int)threadIdx.x;
    const int wave = tid >> 6;
    const int lane = tid & 63;
    const int m16  = lane & 15;
    const int q4   = lane >> 4;
    const int sw   = (m16 & 7) << 3;          // short-granular XOR swizzle

    const int bh = (int)blockIdx.y;
    const int qw = (int)blockIdx.x * 64 + wave * 16;

    __shared__ __align__(16) unsigned short s_k[2][64][64];
    __shared__ __align__(16) unsigned short s_vt[2][64][64];
    __shared__ __align__(16) unsigned short s_p[4][16][64];

    const float* qh = qg + (size_t)bh * Sc * Dc;
    const unsigned short* kbh = kb + (size_t)bh * Sc * Dc;
    const unsigned short* vth = vtb + (size_t)bh * Sc * Dc;
    float* oh = outg + (size_t)bh * Sc * Dc;
    float* ph = attng + (size_t)bh * Sc * Sc;

    // Q A-frag (pre-scaled); also serves as the B-frag of Q^T for the swapped QK^T
    bf16x8 a0, a1;
    {
        const float* qr = qh + (size_t)(qw + m16) * Dc + q4 * 8;
        #pragma unroll
        for (int j = 0; j < 8; ++j) {
            a0[j] = f2bf(qr[j] * kScale);
            a1[j] = f2bf(qr[j + 32] * kScale);
        }
    }

    // ---------------- pass 1: softmax stats; lane owns query qw+m16 ----------------
    float m_i = -1e30f, l_i = 0.0f;

    stage_k_tile(kbh, 0, &s_k[0][0][0], tid);
    __syncthreads();
    for (int t = 0; t < NT; ++t) {
        const int cur = t & 1;
        if (t + 1 < NT) stage_k_tile(kbh, (t + 1) * KC, &s_k[cur ^ 1][0][0], tid);

        float sc[4][4];
        #pragma unroll
        for (int kt = 0; kt < 4; ++kt) {
            const unsigned short* kp = &s_k[cur][kt * 16 + m16][0];
            bf16x8 b0 = *(const bf16x8*)(kp + ((q4 * 8) ^ sw));
            bf16x8 b1 = *(const bf16x8*)(kp + ((q4 * 8 + 32) ^ sw));
            f32x4 c = {0.f, 0.f, 0.f, 0.f};
            c = __builtin_amdgcn_mfma_f32_16x16x32_bf16(b0, a0, c, 0, 0, 0);  // S^T tile
            c = __builtin_amdgcn_mfma_f32_16x16x32_bf16(b1, a1, c, 0, 0, 0);
            #pragma unroll
            for (int r = 0; r < 4; ++r) sc[kt][r] = c[r];
        }

        float tmax = sc[0][0];
        #pragma unroll
        for (int kt = 0; kt < 4; ++kt)
            #pragma unroll
            for (int r = 0; r < 4; ++r) tmax = fmaxf(tmax, sc[kt][r]);
        tmax = fmaxf(tmax, __shfl_xor(tmax, 16));
        tmax = fmaxf(tmax, __shfl_xor(tmax, 32));

        const float mn = fmaxf(m_i, tmax);
        float tsum = 0.f;
        #pragma unroll
        for (int kt = 0; kt < 4; ++kt)
            #pragma unroll
            for (int r = 0; r < 4; ++r) tsum += __expf(sc[kt][r] - mn);
        tsum += __shfl_xor(tsum, 16);
        tsum += __shfl_xor(tsum, 32);

        l_i = l_i * __expf(m_i - mn) + tsum;
        m_i = mn;
        __syncthreads();
    }
    const float inv_l = 1.0f / l_i;

    // ---------------- pass 2: P (vectorized stores) + O = P.V ----------------
    f32x4 o[4];
    #pragma unroll
    for (int dt = 0; dt < 4; ++dt) o[dt] = (f32x4){0.f, 0.f, 0.f, 0.f};

    stage_k_tile(kbh, 0, &s_k[0][0][0], tid);
    stage_vt_tile(vth, 0, &s_vt[0][0][0], tid);
    __syncthreads();
    for (int t = 0; t < NT; ++t) {
        const int cur = t & 1;
        const int k0 = t * KC;
        if (t + 1 < NT) {
            stage_k_tile(kbh, k0 + KC, &s_k[cur ^ 1][0][0], tid);
            stage_vt_tile(vth, k0 + KC, &s_vt[cur ^ 1][0][0], tid);
        }

        #pragma unroll
        for (int kt = 0; kt < 4; ++kt) {
            const unsigned short* kp = &s_k[cur][kt * 16 + m16][0];
            bf16x8 b0 = *(const bf16x8*)(kp + ((q4 * 8) ^ sw));
            bf16x8 b1 = *(const bf16x8*)(kp + ((q4 * 8 + 32) ^ sw));
            f32x4 c = {0.f, 0.f, 0.f, 0.f};
            c = __builtin_amdgcn_mfma_f32_16x16x32_bf16(b0, a0, c, 0, 0, 0);
            c = __builtin_amdgcn_mfma_f32_16x16x32_bf16(b1, a1, c, 0, 0, 0);
            // lane holds P^T[key = k0+kt*16+q4*4+r][q = qw+m16]
            float4 p4;
            p4.x = __expf(c[0] - m_i) * inv_l;
            p4.y = __expf(c[1] - m_i) * inv_l;
            p4.z = __expf(c[2] - m_i) * inv_l;
            p4.w = __expf(c[3] - m_i) * inv_l;
            *(float4*)(ph + (size_t)(qw + m16) * Sc + k0 + kt * 16 + q4 * 4) = p4;
            s16x4 pk;
            pk[0] = f2bf(p4.x); pk[1] = f2bf(p4.y);
            pk[2] = f2bf(p4.z); pk[3] = f2bf(p4.w);
            *(s16x4*)(&s_p[wave][m16][(kt * 16 + q4 * 4) ^ sw]) = pk;
        }

        // O += P.V : pa = A[q][k], vb = B[k][d] from transposed V
        #pragma unroll
        for (int kh2 = 0; kh2 < 2; ++kh2) {
            bf16x8 pa = *(const bf16x8*)(&s_p[wave][m16][(kh2 * 32 + q4 * 8) ^ sw]);
            #pragma unroll
            for (int dt = 0; dt < 4; ++dt) {
                bf16x8 vb = *(const bf16x8*)(&s_vt[cur][dt * 16 + m16][(kh2 * 32 + q4 * 8) ^ sw]);
                o[dt] = __builtin_amdgcn_mfma_f32_16x16x32_bf16(pa, vb, o[dt], 0, 0, 0);
            }
        }
        __syncthreads();
    }

    #pragma unroll
    for (int dt = 0; dt < 4; ++dt)
        #pragma unroll
        for (int r = 0; r < 4; ++r)
            oh[(size_t)(qw + q4 * 4 + r) * Dc + dt * 16 + m16] = o[dt][r];
}

} // namespace

extern "C" void kernel_launch(void* const* d_in, const int* in_sizes, int n_in,
                              void* d_out, int out_size, void* d_ws, size_t ws_size,
                              hipStream_t stream) {
    (void)in_sizes; (void)n_in; (void)out_size; (void)ws_size;
    const float* q = (const float*)d_in[0];
    const float* k = (const float*)d_in[1];
    const float* v = (const float*)d_in[2];
    float* out  = (float*)d_out;
    float* attn = out + (size_t)Bc * Hc * Sc * Dc;   // outputs concatenated: out, attn

    const size_t n = (size_t)Bc * Hc * Sc * Dc;
    unsigned short* kb  = (unsigned short*)d_ws;     // bf16 K, swizzled   (8.4 MB)
    unsigned short* vtb = kb + n;                    // bf16 V^T, swizzled (8.4 MB)

    dim3 grid(Sc / KC, Bc * Hc);
    prep<<<grid, 256, 0, stream>>>(k, v, kb, vtb);
    fa_fwd<<<grid, 256, 0, stream>>>(q, kb, vtb, out, attn);
}

// Round 2
// 647.095 us; speedup vs baseline: 1.3189x; 1.0657x over previous
//
#include <hip/hip_runtime.h>

namespace {

constexpr int Bc = 2, Hc = 16, Sc = 2048, Dc = 64;
constexpr int KC = 64;             // keys per chunk
constexpr int NT = Sc / KC;        // 32 chunks
// 1/sqrt(64) * log2(e): softmax computed in base-2 domain (cancels exactly)
constexpr float kQScale = 0.125f * 1.4426950408889634f;

typedef __attribute__((ext_vector_type(8))) short bf16x8;
typedef __attribute__((ext_vector_type(4))) short s16x4;
typedef __attribute__((ext_vector_type(4))) float f32x4;

__device__ inline short f2bf(float x) {
    union { float f; unsigned int u; } v;
    v.f = x;
    unsigned int r = v.u + 0x7fffu + ((v.u >> 16) & 1u);
    return (short)(r >> 16);
}

// ---------------- prep: K and V^T -> bf16 fragment-ordered buffers ----------------
// K fragment buffer kf (per head, Sc*Dc shorts):
//   kf[(((row>>4)*2 + half)*64 + (row&15) + 16*q4)*8 + j] = bf16(K[row][half*32 + q4*8 + j])
//   -> a wave's b0/b1 loads for a 16-key tile are one contiguous 1KB line (lane*16B).
// V fragment buffer vf (per head, Sc*Dc shorts):
//   vf[((g*4 + dt)*64 + m16 + 16*q4)*8 + j] = bf16(V[g*32 + q4*8 + j][dt*16 + m16])
//   (g = 32-key group) -> PV B-fragments are contiguous 1KB lines too.
__global__ __launch_bounds__(256)
void prep(const float* __restrict__ kg, const float* __restrict__ vg,
          unsigned short* __restrict__ kf, unsigned short* __restrict__ vf) {
    const int tid = (int)threadIdx.x;
    const int bh = (int)blockIdx.y;
    const int k0 = (int)blockIdx.x * KC;
    const float* kh = kg + (size_t)bh * Sc * Dc;
    const float* vh = vg + (size_t)bh * Sc * Dc;
    unsigned short* kfh = kf + (size_t)bh * Sc * Dc;
    unsigned short* vfh = vf + (size_t)bh * Sc * Dc;

    __shared__ float sv[64][65];

    // stage V tile (f32) for transpose
    #pragma unroll
    for (int it = 0; it < 4; ++it) {
        int fid = tid + it * 256;
        int row = fid >> 4, c4 = (fid & 15) * 4;
        float4 tv = *(const float4*)(vh + (size_t)(k0 + row) * Dc + c4);
        sv[row][c4 + 0] = tv.x; sv[row][c4 + 1] = tv.y;
        sv[row][c4 + 2] = tv.z; sv[row][c4 + 3] = tv.w;
    }

    // K fragments straight from global (row-major read, fragment-order write)
    #pragma unroll
    for (int it = 0; it < 2; ++it) {
        int idx = tid + it * 256;
        int r = idx >> 3, g8 = idx & 7;          // row-in-tile, 8-elem d-group
        int row = k0 + r;
        const float* kr = kh + (size_t)row * Dc + g8 * 8;
        float4 t0 = *(const float4*)kr;
        float4 t1 = *(const float4*)(kr + 4);
        bf16x8 kv;
        kv[0] = f2bf(t0.x); kv[1] = f2bf(t0.y); kv[2] = f2bf(t0.z); kv[3] = f2bf(t0.w);
        kv[4] = f2bf(t1.x); kv[5] = f2bf(t1.y); kv[6] = f2bf(t1.z); kv[7] = f2bf(t1.w);
        int di = (((row >> 4) * 2 + (g8 >> 2)) * 64 + (row & 15) + ((g8 & 3) << 4)) * 8;
        *(bf16x8*)(kfh + di) = kv;
    }
    __syncthreads();

    // V^T fragments from the staged tile
    #pragma unroll
    for (int it = 0; it < 2; ++it) {
        int idx = tid + it * 256;
        int d = idx >> 3, o = idx & 7;           // d-row, key-octet
        int g = (k0 >> 5) + (o >> 2);            // global 32-key group
        bf16x8 vv;
        #pragma unroll
        for (int i = 0; i < 8; ++i) vv[i] = f2bf(sv[o * 8 + i][d]);
        int di = ((g * 4 + (d >> 4)) * 64 + (d & 15) + ((o & 3) << 4)) * 8;
        *(bf16x8*)(vfh + di) = vv;
    }
}

// ---------------- main: barrier-free, fragments streamed from L2 ----------------
__global__ __launch_bounds__(256, 4)
void fa_fwd(const float* __restrict__ qg, const unsigned short* __restrict__ kf,
            const unsigned short* __restrict__ vf, float* __restrict__ outg,
            float* __restrict__ attng) {
    const int tid  = (int)threadIdx.x;
    const int wave = tid >> 6;
    const int lane = tid & 63;
    const int m16  = lane & 15;
    const int q4   = lane >> 4;
    const int sw   = (m16 & 7) << 3;      // s_p bank swizzle (shorts)

    // XCD-bijective remap: all 32 q-blocks of a head share one XCD's L2
    const int flat = (int)blockIdx.x;                 // grid = 1024 blocks
    const int bh   = (((flat >> 8) & 3) << 3) | (flat & 7);
    const int qb   = (flat >> 3) & 31;
    const int qw   = qb * 64 + wave * 16;

    // only LDS: per-wave P transpose buffer (C-layout -> A-layout), no barriers
    __shared__ __align__(16) unsigned short s_p[4][16][64];

    const float* qh = qg + (size_t)bh * Sc * Dc;
    const unsigned short* kfh = kf + (size_t)bh * Sc * Dc;
    const unsigned short* vfh = vf + (size_t)bh * Sc * Dc;
    float* oh = outg + (size_t)bh * Sc * Dc;
    float* ph = attng + (size_t)bh * Sc * Sc;

    // Q fragment (pre-scaled into base-2 domain); B-operand of the swapped QK^T
    bf16x8 a0, a1;
    {
        const float* qr = qh + (size_t)(qw + m16) * Dc + q4 * 8;
        #pragma unroll
        for (int j = 0; j < 8; ++j) {
            a0[j] = f2bf(qr[j] * kQScale);
            a1[j] = f2bf(qr[j + 32] * kQScale);
        }
    }

    const unsigned short* kl = kfh + lane * 8;
    const unsigned short* vl = vfh + lane * 8;

    // ---------------- pass 1: softmax stats; lane owns query qw+m16 ----------------
    float m_i = -1e30f, l_i = 0.0f;
    for (int t = 0; t < NT; ++t) {
        const unsigned short* kt_base = kl + t * 4096;
        float sc[4][4];
        #pragma unroll
        for (int kt = 0; kt < 4; ++kt) {
            bf16x8 b0 = *(const bf16x8*)(kt_base + kt * 1024);
            bf16x8 b1 = *(const bf16x8*)(kt_base + kt * 1024 + 512);
            f32x4 c = {0.f, 0.f, 0.f, 0.f};
            c = __builtin_amdgcn_mfma_f32_16x16x32_bf16(b0, a0, c, 0, 0, 0); // S^T
            c = __builtin_amdgcn_mfma_f32_16x16x32_bf16(b1, a1, c, 0, 0, 0);
            #pragma unroll
            for (int r = 0; r < 4; ++r) sc[kt][r] = c[r];
        }
        float tmax = sc[0][0];
        #pragma unroll
        for (int kt = 0; kt < 4; ++kt)
            #pragma unroll
            for (int r = 0; r < 4; ++r) tmax = fmaxf(tmax, sc[kt][r]);
        tmax = fmaxf(tmax, __shfl_xor(tmax, 16));
        tmax = fmaxf(tmax, __shfl_xor(tmax, 32));

        const float mn = fmaxf(m_i, tmax);
        float tsum = 0.f;
        #pragma unroll
        for (int kt = 0; kt < 4; ++kt)
            #pragma unroll
            for (int r = 0; r < 4; ++r) tsum += exp2f(sc[kt][r] - mn);
        tsum += __shfl_xor(tsum, 16);
        tsum += __shfl_xor(tsum, 32);

        l_i = l_i * exp2f(m_i - mn) + tsum;
        m_i = mn;
    }
    const float inv_l = 1.0f / l_i;

    // ---------------- pass 2: normalized P (vectorized nt stores) + O = P.V ----------------
    f32x4 o[4];
    #pragma unroll
    for (int dt = 0; dt < 4; ++dt) o[dt] = (f32x4){0.f, 0.f, 0.f, 0.f};

    for (int t = 0; t < NT; ++t) {
        const unsigned short* kt_base = kl + t * 4096;
        const unsigned short* vt_base = vl + t * 4096;

        #pragma unroll
        for (int kt = 0; kt < 4; ++kt) {
            bf16x8 b0 = *(const bf16x8*)(kt_base + kt * 1024);
            bf16x8 b1 = *(const bf16x8*)(kt_base + kt * 1024 + 512);
            f32x4 c = {0.f, 0.f, 0.f, 0.f};
            c = __builtin_amdgcn_mfma_f32_16x16x32_bf16(b0, a0, c, 0, 0, 0);
            c = __builtin_amdgcn_mfma_f32_16x16x32_bf16(b1, a1, c, 0, 0, 0);
            // lane holds P^T[key = t*64+kt*16+q4*4+r][q = qw+m16]
            f32x4 p4;
            #pragma unroll
            for (int r = 0; r < 4; ++r) p4[r] = exp2f(c[r] - m_i) * inv_l;
            __builtin_nontemporal_store(
                p4, (f32x4*)(ph + (size_t)(qw + m16) * Sc + t * 64 + kt * 16 + q4 * 4));
            s16x4 pk;
            pk[0] = f2bf(p4[0]); pk[1] = f2bf(p4[1]);
            pk[2] = f2bf(p4[2]); pk[3] = f2bf(p4[3]);
            *(s16x4*)(&s_p[wave][m16][(kt * 16 + q4 * 4) ^ sw]) = pk;
        }

        // O += P.V  (pa from per-wave LDS transpose, vb straight from L2)
        #pragma unroll
        for (int kh2 = 0; kh2 < 2; ++kh2) {
            bf16x8 pa = *(const bf16x8*)(&s_p[wave][m16][(kh2 * 32 + q4 * 8) ^ sw]);
            #pragma unroll
            for (int dt = 0; dt < 4; ++dt) {
                bf16x8 vb = *(const bf16x8*)(vt_base + kh2 * 2048 + dt * 512);
                o[dt] = __builtin_amdgcn_mfma_f32_16x16x32_bf16(pa, vb, o[dt], 0, 0, 0);
            }
        }
    }

    #pragma unroll
    for (int dt = 0; dt < 4; ++dt)
        #pragma unroll
        for (int r = 0; r < 4; ++r)
            oh[(size_t)(qw + q4 * 4 + r) * Dc + dt * 16 + m16] = o[dt][r];
}

} // namespace

extern "C" void kernel_launch(void* const* d_in, const int* in_sizes, int n_in,
                              void* d_out, int out_size, void* d_ws, size_t ws_size,
                              hipStream_t stream) {
    (void)in_sizes; (void)n_in; (void)out_size; (void)ws_size;
    const float* q = (const float*)d_in[0];
    const float* k = (const float*)d_in[1];
    const float* v = (const float*)d_in[2];
    float* out  = (float*)d_out;
    float* attn = out + (size_t)Bc * Hc * Sc * Dc;   // outputs concatenated: out, attn

    const size_t n = (size_t)Bc * Hc * Sc * Dc;
    unsigned short* kf = (unsigned short*)d_ws;      // bf16 K fragments   (8.4 MB)
    unsigned short* vf = kf + n;                     // bf16 V^T fragments (8.4 MB)

    prep<<<dim3(Sc / KC, Bc * Hc), 256, 0, stream>>>(k, v, kf, vf);
    fa_fwd<<<dim3((Sc / 64) * Bc * Hc), 256, 0, stream>>>(q, kf, vf, out, attn);
}